// Round 7
// baseline (2948.220 us; speedup 1.0000x reference)
//
#include <hip/hip_runtime.h>
#include <hip/hip_bf16.h>

#define NB   64     // batch
#define NS   128    // seq len
#define ND   256    // embed dim
#define NU   512    // hidden units
#define N3   1536   // 3*NU

typedef __attribute__((ext_vector_type(4))) float  f32x4;
typedef __attribute__((ext_vector_type(8))) short  s16x8;
typedef unsigned long long u64;
typedef unsigned int       u32;
typedef unsigned short     u16;

// bf16 NaN sentinel: legit h in [-1,1] -> bit14 clear; sentinel has bit14 set.
#define SENT64  0x7FC07FC07FC07FC0ull
#define BIT14x4 0x4000400040004000ull

__device__ __forceinline__ u16 f2bf(float v) {
  unsigned u = __builtin_bit_cast(unsigned, v);
  u += 0x7fffu + ((u >> 16) & 1u);          // round-to-nearest-even
  return (u16)(u >> 16);
}

// -------- init: hx slot0 = bf16(hidden); slots 1..127 = sentinel ---------------
__global__ __launch_bounds__(512) void init_kernel(const float* __restrict__ hidden,
                                                   u16* __restrict__ hx) {
  const int tid = blockIdx.x * 512 + threadIdx.x;    // 64*512 = 32768 = NB*NU
  hx[tid] = f2bf(hidden[tid]);                       // slot 0 (t=0)
  u64* fill = (u64*)(hx + NB * NU);
  const int n = 127 * NB * NU / 4;
  for (int i = tid; i < n; i += NB * NU) fill[i] = SENT64;
}

// -------- phase 1: xp = gather(emb,x) @ W + b_in  (f32 SIMT, unchanged) --------
__global__ __launch_bounds__(256) void xproj_kernel(
    const int* __restrict__ x, const float* __restrict__ emb,
    const float* __restrict__ W, const float* __restrict__ bias,
    float* __restrict__ xp) {
  __shared__ float As[32][68];
  __shared__ float Bs[32][68];
  __shared__ int tok[64];
  const int tid = threadIdx.x;
  const int m0 = blockIdx.y * 64;
  const int n0 = blockIdx.x * 64;
  if (tid < 64) tok[tid] = x[m0 + tid];
  __syncthreads();
  const int tx = tid & 15, ty = tid >> 4;
  float acc[4][4] = {};
  for (int k0 = 0; k0 < ND; k0 += 32) {
    {
      const int m = tid & 63, kq = tid >> 6;
      const float* src = emb + (size_t)tok[m] * ND + k0 + kq * 8;
      const float4 v0 = *(const float4*)(src);
      const float4 v1 = *(const float4*)(src + 4);
      As[kq*8+0][m] = v0.x; As[kq*8+1][m] = v0.y;
      As[kq*8+2][m] = v0.z; As[kq*8+3][m] = v0.w;
      As[kq*8+4][m] = v1.x; As[kq*8+5][m] = v1.y;
      As[kq*8+6][m] = v1.z; As[kq*8+7][m] = v1.w;
    }
    {
      const int n = (tid & 15) * 4, k = tid >> 4;
      *(float4*)&Bs[k][n]    = *(const float4*)&W[(size_t)(k0 + k) * N3 + n0 + n];
      *(float4*)&Bs[k+16][n] = *(const float4*)&W[(size_t)(k0 + k + 16) * N3 + n0 + n];
    }
    __syncthreads();
    #pragma unroll
    for (int kk = 0; kk < 32; ++kk) {
      const float4 b4 = *(const float4*)&Bs[kk][tx * 4];
      float a[4];
      #pragma unroll
      for (int i = 0; i < 4; ++i) a[i] = As[kk][ty * 4 + i];
      #pragma unroll
      for (int i = 0; i < 4; ++i) {
        acc[i][0] += a[i] * b4.x;
        acc[i][1] += a[i] * b4.y;
        acc[i][2] += a[i] * b4.z;
        acc[i][3] += a[i] * b4.w;
      }
    }
    __syncthreads();
  }
  #pragma unroll
  for (int i = 0; i < 4; ++i) {
    const size_t row = (size_t)(m0 + ty * 4 + i) * N3 + n0 + tx * 4;
    float4 o;
    o.x = acc[i][0] + bias[n0 + tx*4 + 0];
    o.y = acc[i][1] + bias[n0 + tx*4 + 1];
    o.z = acc[i][2] + bias[n0 + tx*4 + 2];
    o.w = acc[i][3] + bias[n0 + tx*4 + 3];
    *(float4*)&xp[row] = o;
  }
}

// -------- phase 2: persistent GRU scan, chain-interleaved latency hiding -------
// 16 blocks, each owns 32 units for ALL 4 independent batch-chains, processed
// round-robin: phase g of iteration t computes chain g step t. Chain g's h is
// produced at phase g and consumed at phase g of the NEXT iteration (loads
// issued one phase early) -> cross-block visibility latency has a 3-phase
// compute window to complete. R fragments live in REGISTERS (48 s16x8/lane);
// no LDS and no sync primitives in the loop; sentinel poll-on-data.

#define LOADSLABS(BUF_, G_, T_) do {                                            \
    const u64* hq_ = (const u64*)(hx + ((size_t)(T_) * NB + ((G_) << 4) + ar) * NU); \
    _Pragma("unroll")                                                           \
    for (int ks_ = 0; ks_ < 16; ++ks_) {                                        \
      BUF_[2*ks_]   = __hip_atomic_load(&hq_[ks_*8 + kg*2],                     \
                        __ATOMIC_RELAXED, __HIP_MEMORY_SCOPE_AGENT);            \
      BUF_[2*ks_+1] = __hip_atomic_load(&hq_[ks_*8 + kg*2 + 1],                 \
                        __ATOMIC_RELAXED, __HIP_MEMORY_SCOPE_AGENT);            \
    }                                                                           \
  } while (0)

#define LOADXP(XZ_, XR_, XH_, G_, T_) do {                                      \
    _Pragma("unroll")                                                           \
    for (int i_ = 0; i_ < 4; ++i_) {                                            \
      const float* q_ = xp + ((size_t)((((G_) << 4) + drow + i_) * NS) + (T_)) * N3 + myu; \
      XZ_[i_] = q_[0]; XR_[i_] = q_[512]; XH_[i_] = q_[1024];                   \
    }                                                                           \
  } while (0)

#define PHASE(T_, G_, CUR_, NXT_, XZC_, XRC_, XHC_, XZN_, XRN_, XHN_, GN_, TN_) do { \
    LOADSLABS(NXT_, GN_, TN_);            /* prefetch next phase's slabs */     \
    LOADXP(XZN_, XRN_, XHN_, GN_, TN_);   /* prefetch next phase's xp    */     \
    { u64 m_ = 0;                                                               \
      _Pragma("unroll") for (int q_ = 0; q_ < 32; ++q_) m_ |= CUR_[q_];         \
      int ok_ = ((m_ & BIT14x4) == 0) ? 1 : 0;                                  \
      while (!__all(ok_)) {                                                     \
        if (!ok_) {                                                             \
          LOADSLABS(CUR_, G_, T_);                                              \
          m_ = 0;                                                               \
          _Pragma("unroll") for (int q_ = 0; q_ < 32; ++q_) m_ |= CUR_[q_];     \
          ok_ = ((m_ & BIT14x4) == 0) ? 1 : 0;                                  \
        }                                                                       \
      }                                                                         \
    }                                                                           \
    f32x4 a0_ = {0.f,0.f,0.f,0.f}, a1_ = a0_, a2_ = a0_;                        \
    _Pragma("unroll")                                                           \
    for (int ks_ = 0; ks_ < 16; ++ks_) {                                        \
      union { u64 q[2]; s16x8 v; } af_;                                         \
      af_.q[0] = CUR_[2*ks_]; af_.q[1] = CUR_[2*ks_+1];                         \
      a0_ = __builtin_amdgcn_mfma_f32_16x16x32_bf16(af_.v, bfr[ks_],      a0_, 0,0,0); \
      a1_ = __builtin_amdgcn_mfma_f32_16x16x32_bf16(af_.v, bfr[16 + ks_], a1_, 0,0,0); \
      a2_ = __builtin_amdgcn_mfma_f32_16x16x32_bf16(af_.v, bfr[32 + ks_], a2_, 0,0,0); \
    }                                                                           \
    _Pragma("unroll")                                                           \
    for (int i_ = 0; i_ < 4; ++i_) {                                            \
      const float z_ = 1.f / (1.f + __expf(-(XZC_[i_] + a0_[i_] + bz)));        \
      const float r_ = 1.f / (1.f + __expf(-(XRC_[i_] + a1_[i_] + br)));        \
      const float e_ = __expf(2.f * (XHC_[i_] + r_ * (a2_[i_] + bh)));          \
      const float hh_ = 1.f - 2.f / (e_ + 1.f);   /* tanh, never NaN/Inf */     \
      hr[G_][i_] = z_ * hr[G_][i_] + (1.f - z_) * hh_;                          \
    }                                                                           \
    if ((T_) < NS - 1) {                                                        \
      _Pragma("unroll")                                                         \
      for (int i_ = 0; i_ < 4; ++i_)                                            \
        __hip_atomic_store(&hx[((size_t)((T_) + 1) * NB + ((G_) << 4) + drow + i_) * NU + myu], \
                           f2bf(hr[G_][i_]), __ATOMIC_RELAXED, __HIP_MEMORY_SCOPE_AGENT); \
    }                                                                           \
    _Pragma("unroll")                                                           \
    for (int i_ = 0; i_ < 4; ++i_)                                              \
      out[((size_t)(((G_) << 4) + drow + i_) * NS + (T_)) * NU + myu] = hr[G_][i_]; \
    if ((T_) == NS - 1) {                                                       \
      _Pragma("unroll")                                                         \
      for (int i_ = 0; i_ < 4; ++i_)                                            \
        out[(size_t)NB * NS * NU + (size_t)(((G_) << 4) + drow + i_) * NU + myu] = hr[G_][i_]; \
    }                                                                           \
  } while (0)

__global__ __launch_bounds__(128, 1) void gru_scan_kernel(
    const float* __restrict__ xp, const float* __restrict__ hidden,
    const float* __restrict__ R, const float* __restrict__ bias,
    float* __restrict__ out, u16* __restrict__ hx) {
  __shared__ u16 Rt[96][520];   // staging only (dead after bfr load)

  const int bid = blockIdx.x;        // 0..15: unit-block
  const int u0  = bid * 32;          // unit base
  const int tid = threadIdx.x;
  const int lane = tid & 63;
  const int wv   = tid >> 6;

  // one-time: stage R columns transposed to bf16, remapped per-wave
  for (int idx = tid; idx < 512 * 128; idx += 128) {
    const int k = idx >> 7, c = idx & 127;
    if (c < 96) {
      const int wc = c / 48, r = c % 48, j = r >> 4, cuu = r & 15;
      Rt[c][k] = f2bf(R[(size_t)k * N3 + (j << 9) + u0 + (wc << 4) + cuu]);
    }
  }
  __syncthreads();

  const int ar  = lane & 15;              // A row (batch within chain)
  const int kg  = lane >> 4;              // k-group
  const int cu  = lane & 15;              // unit within wave slice
  const int myu = u0 + (wv << 4) + cu;    // my global unit
  const int drow = kg << 2;               // batch base for D rows
  const int cb  = wv * 48 + cu;           // Rt row base

  // R fragments -> registers: 48 x s16x8 (192 VGPR)
  s16x8 bfr[48];
  #pragma unroll
  for (int j = 0; j < 3; ++j)
    #pragma unroll
    for (int ks = 0; ks < 16; ++ks)
      bfr[j * 16 + ks] = *(const s16x8*)&Rt[cb + 16 * j][ks * 32 + kg * 8];

  const float bz = bias[N3 + myu];
  const float br = bias[N3 + 512 + myu];
  const float bh = bias[N3 + 1024 + myu];

  float hr[4][4];
  #pragma unroll
  for (int G = 0; G < 4; ++G)
    #pragma unroll
    for (int i = 0; i < 4; ++i)
      hr[G][i] = hidden[(size_t)((G << 4) + drow + i) * NU + myu];

  u64 s0[32], s1[32];
  float xz0[4], xr0[4], xh0[4], xz1[4], xr1[4], xh1[4];
  LOADSLABS(s0, 0, 0);
  LOADXP(xz0, xr0, xh0, 0, 0);

  for (int t = 0; t < NS; ++t) {
    const int tn = (t + 1 < NS) ? t + 1 : 0;   // wrap target is read-valid, unused
    PHASE(t, 0, s0, s1, xz0, xr0, xh0, xz1, xr1, xh1, 1, t);
    PHASE(t, 1, s1, s0, xz1, xr1, xh1, xz0, xr0, xh0, 2, t);
    PHASE(t, 2, s0, s1, xz0, xr0, xh0, xz1, xr1, xh1, 3, t);
    PHASE(t, 3, s1, s0, xz1, xr1, xh1, xz0, xr0, xh0, 0, tn);
  }
}

extern "C" void kernel_launch(void* const* d_in, const int* in_sizes, int n_in,
                              void* d_out, int out_size, void* d_ws, size_t ws_size,
                              hipStream_t stream) {
  const int*   x      = (const int*)d_in[0];
  const float* hidden = (const float*)d_in[1];
  const float* emb    = (const float*)d_in[2];
  const float* W      = (const float*)d_in[3];
  const float* R      = (const float*)d_in[4];
  const float* bias   = (const float*)d_in[5];
  float* out = (float*)d_out;

  char* ws = (char*)d_ws;
  float* xp  = (float*)ws;                            // 50,331,648 B
  u16*   hx  = (u16*)(ws + 50331648);                 //  8,388,608 B (128 slots)

  init_kernel<<<NB, NU, 0, stream>>>(hidden, hx);
  dim3 gA(N3 / 64, (NB * NS) / 64);
  xproj_kernel<<<gA, 256, 0, stream>>>(x, emb, W, bias, xp);
  gru_scan_kernel<<<16, 128, 0, stream>>>(xp, hidden, R, bias, out, hx);
}

// Round 8
// 2027.044 us; speedup vs baseline: 1.4544x; 1.4544x over previous
//
#include <hip/hip_runtime.h>
#include <hip/hip_bf16.h>

#define NB   64     // batch
#define NS   128    // seq len
#define ND   256    // embed dim
#define NU   512    // hidden units
#define N3   1536   // 3*NU

typedef __attribute__((ext_vector_type(4))) float  f32x4;
typedef __attribute__((ext_vector_type(8))) short  s16x8;
typedef unsigned long long u64;
typedef unsigned int       u32;
typedef unsigned short     u16;

// bf16 NaN sentinel: legit h in [-1,1] -> bit14 clear; sentinel has bit14 set.
#define SENT64  0x7FC07FC07FC07FC0ull
#define BIT14x4 0x4000400040004000ull

__device__ __forceinline__ u16 f2bf(float v) {
  unsigned u = __builtin_bit_cast(unsigned, v);
  u += 0x7fffu + ((u >> 16) & 1u);          // round-to-nearest-even
  return (u16)(u >> 16);
}

// -------- init: hx slot0 = bf16(hidden); slots 1..127 = sentinel ---------------
__global__ __launch_bounds__(512) void init_kernel(const float* __restrict__ hidden,
                                                   u16* __restrict__ hx) {
  const int tid = blockIdx.x * 512 + threadIdx.x;    // 64*512 = 32768 = NB*NU
  hx[tid] = f2bf(hidden[tid]);                       // slot 0 (t=0)
  u64* fill = (u64*)(hx + NB * NU);
  const int n = 127 * NB * NU / 4;
  for (int i = tid; i < n; i += NB * NU) fill[i] = SENT64;
}

// -------- phase 1: xp = gather(emb,x) @ W + b_in  (f32 SIMT, unchanged) --------
__global__ __launch_bounds__(256) void xproj_kernel(
    const int* __restrict__ x, const float* __restrict__ emb,
    const float* __restrict__ W, const float* __restrict__ bias,
    float* __restrict__ xp) {
  __shared__ float As[32][68];
  __shared__ float Bs[32][68];
  __shared__ int tok[64];
  const int tid = threadIdx.x;
  const int m0 = blockIdx.y * 64;
  const int n0 = blockIdx.x * 64;
  if (tid < 64) tok[tid] = x[m0 + tid];
  __syncthreads();
  const int tx = tid & 15, ty = tid >> 4;
  float acc[4][4] = {};
  for (int k0 = 0; k0 < ND; k0 += 32) {
    {
      const int m = tid & 63, kq = tid >> 6;
      const float* src = emb + (size_t)tok[m] * ND + k0 + kq * 8;
      const float4 v0 = *(const float4*)(src);
      const float4 v1 = *(const float4*)(src + 4);
      As[kq*8+0][m] = v0.x; As[kq*8+1][m] = v0.y;
      As[kq*8+2][m] = v0.z; As[kq*8+3][m] = v0.w;
      As[kq*8+4][m] = v1.x; As[kq*8+5][m] = v1.y;
      As[kq*8+6][m] = v1.z; As[kq*8+7][m] = v1.w;
    }
    {
      const int n = (tid & 15) * 4, k = tid >> 4;
      *(float4*)&Bs[k][n]    = *(const float4*)&W[(size_t)(k0 + k) * N3 + n0 + n];
      *(float4*)&Bs[k+16][n] = *(const float4*)&W[(size_t)(k0 + k + 16) * N3 + n0 + n];
    }
    __syncthreads();
    #pragma unroll
    for (int kk = 0; kk < 32; ++kk) {
      const float4 b4 = *(const float4*)&Bs[kk][tx * 4];
      float a[4];
      #pragma unroll
      for (int i = 0; i < 4; ++i) a[i] = As[kk][ty * 4 + i];
      #pragma unroll
      for (int i = 0; i < 4; ++i) {
        acc[i][0] += a[i] * b4.x;
        acc[i][1] += a[i] * b4.y;
        acc[i][2] += a[i] * b4.z;
        acc[i][3] += a[i] * b4.w;
      }
    }
    __syncthreads();
  }
  #pragma unroll
  for (int i = 0; i < 4; ++i) {
    const size_t row = (size_t)(m0 + ty * 4 + i) * N3 + n0 + tx * 4;
    float4 o;
    o.x = acc[i][0] + bias[n0 + tx*4 + 0];
    o.y = acc[i][1] + bias[n0 + tx*4 + 1];
    o.z = acc[i][2] + bias[n0 + tx*4 + 2];
    o.w = acc[i][3] + bias[n0 + tx*4 + 3];
    *(float4*)&xp[row] = o;
  }
}

// -------- phase 2: persistent GRU scan, chain-interleaved latency hiding -------
// 16 blocks, each owns 32 units for ALL 4 independent batch-chains, round-robin:
// phase g of iteration t computes chain g step t. Chain g's h is produced 3
// phases before its consuming load is issued (and 4 before the sentinel check),
// so cross-block store->visible latency hides under compute. R stays in LDS
// (read per-MFMA via ds_read_b128) so registers hold only the slab/xp double
// buffers -> ~220 VGPR, NO SPILL (R7's failure mode).

#define LOADSLABS(BUF_, G_, T_) do {                                            \
    const u64* hq_ = (const u64*)(hx + ((size_t)(T_) * NB + ((G_) << 4) + ar) * NU); \
    _Pragma("unroll")                                                           \
    for (int ks_ = 0; ks_ < 16; ++ks_) {                                        \
      BUF_[2*ks_]   = __hip_atomic_load(&hq_[ks_*8 + kg*2],                     \
                        __ATOMIC_RELAXED, __HIP_MEMORY_SCOPE_AGENT);            \
      BUF_[2*ks_+1] = __hip_atomic_load(&hq_[ks_*8 + kg*2 + 1],                 \
                        __ATOMIC_RELAXED, __HIP_MEMORY_SCOPE_AGENT);            \
    }                                                                           \
  } while (0)

#define LOADXP(XZ_, XR_, XH_, G_, T_) do {                                      \
    _Pragma("unroll")                                                           \
    for (int i_ = 0; i_ < 4; ++i_) {                                            \
      const float* q_ = xp + ((size_t)((((G_) << 4) + drow + i_) * NS) + (T_)) * N3 + myu; \
      XZ_[i_] = q_[0]; XR_[i_] = q_[512]; XH_[i_] = q_[1024];                   \
    }                                                                           \
  } while (0)

#define PHASE(T_, G_, CUR_, NXT_, XZC_, XRC_, XHC_, XZN_, XRN_, XHN_, GN_, TN_) do { \
    LOADSLABS(NXT_, GN_, TN_);            /* prefetch next phase's slabs */     \
    LOADXP(XZN_, XRN_, XHN_, GN_, TN_);   /* prefetch next phase's xp    */     \
    { u64 m_ = 0;                                                               \
      _Pragma("unroll") for (int q_ = 0; q_ < 32; ++q_) m_ |= CUR_[q_];         \
      int ok_ = ((m_ & BIT14x4) == 0) ? 1 : 0;                                  \
      while (!__all(ok_)) {                                                     \
        if (!ok_) {                                                             \
          LOADSLABS(CUR_, G_, T_);                                              \
          m_ = 0;                                                               \
          _Pragma("unroll") for (int q_ = 0; q_ < 32; ++q_) m_ |= CUR_[q_];     \
          ok_ = ((m_ & BIT14x4) == 0) ? 1 : 0;                                  \
        }                                                                       \
      }                                                                         \
    }                                                                           \
    f32x4 a0_ = {0.f,0.f,0.f,0.f}, a1_ = a0_, a2_ = a0_;                        \
    _Pragma("unroll")                                                           \
    for (int ks_ = 0; ks_ < 16; ++ks_) {                                        \
      union { u64 q[2]; s16x8 v; } af_;                                         \
      af_.q[0] = CUR_[2*ks_]; af_.q[1] = CUR_[2*ks_+1];                         \
      const int kb_ = (ks_ << 5) + (kg << 3);                                   \
      a0_ = __builtin_amdgcn_mfma_f32_16x16x32_bf16(af_.v, *(const s16x8*)&Rt[cb][kb_],      a0_, 0,0,0); \
      a1_ = __builtin_amdgcn_mfma_f32_16x16x32_bf16(af_.v, *(const s16x8*)&Rt[cb + 16][kb_], a1_, 0,0,0); \
      a2_ = __builtin_amdgcn_mfma_f32_16x16x32_bf16(af_.v, *(const s16x8*)&Rt[cb + 32][kb_], a2_, 0,0,0); \
    }                                                                           \
    _Pragma("unroll")                                                           \
    for (int i_ = 0; i_ < 4; ++i_) {                                            \
      const float z_ = 1.f / (1.f + __expf(-(XZC_[i_] + a0_[i_] + bz)));        \
      const float r_ = 1.f / (1.f + __expf(-(XRC_[i_] + a1_[i_] + br)));        \
      const float e_ = __expf(2.f * (XHC_[i_] + r_ * (a2_[i_] + bh)));          \
      const float hh_ = 1.f - 2.f / (e_ + 1.f);   /* tanh, never NaN/Inf */     \
      hr[G_][i_] = z_ * hr[G_][i_] + (1.f - z_) * hh_;                          \
    }                                                                           \
    if ((T_) < NS - 1) {                                                        \
      _Pragma("unroll")                                                         \
      for (int i_ = 0; i_ < 4; ++i_)                                            \
        __hip_atomic_store(&hx[((size_t)((T_) + 1) * NB + ((G_) << 4) + drow + i_) * NU + myu], \
                           f2bf(hr[G_][i_]), __ATOMIC_RELAXED, __HIP_MEMORY_SCOPE_AGENT); \
    }                                                                           \
    _Pragma("unroll")                                                           \
    for (int i_ = 0; i_ < 4; ++i_)                                              \
      out[((size_t)(((G_) << 4) + drow + i_) * NS + (T_)) * NU + myu] = hr[G_][i_]; \
    if ((T_) == NS - 1) {                                                       \
      _Pragma("unroll")                                                         \
      for (int i_ = 0; i_ < 4; ++i_)                                            \
        out[(size_t)NB * NS * NU + (size_t)(((G_) << 4) + drow + i_) * NU + myu] = hr[G_][i_]; \
    }                                                                           \
  } while (0)

__global__ __launch_bounds__(128, 1) void gru_scan_kernel(
    const float* __restrict__ xp, const float* __restrict__ hidden,
    const float* __restrict__ R, const float* __restrict__ bias,
    float* __restrict__ out, u16* __restrict__ hx) {
  __shared__ u16 Rt[96][520];   // [c][k]: c = wv*48 + gate*16 + cu  (resident)

  const int bid = blockIdx.x;        // 0..15: unit-block
  const int u0  = bid * 32;          // unit base
  const int tid = threadIdx.x;
  const int lane = tid & 63;
  const int wv   = tid >> 6;

  // one-time: stage R columns transposed to bf16, remapped per-wave
  for (int idx = tid; idx < 512 * 128; idx += 128) {
    const int k = idx >> 7, c = idx & 127;
    if (c < 96) {
      const int wc = c / 48, r = c % 48, j = r >> 4, cuu = r & 15;
      Rt[c][k] = f2bf(R[(size_t)k * N3 + (j << 9) + u0 + (wc << 4) + cuu]);
    }
  }
  __syncthreads();

  const int ar  = lane & 15;              // A row (batch within chain)
  const int kg  = lane >> 4;              // k-group
  const int cu  = lane & 15;              // unit within wave slice
  const int myu = u0 + (wv << 4) + cu;    // my global unit
  const int drow = kg << 2;               // batch base for D rows
  const int cb  = wv * 48 + cu;           // Rt row base

  const float bz = bias[N3 + myu];
  const float br = bias[N3 + 512 + myu];
  const float bh = bias[N3 + 1024 + myu];

  float hr[4][4];
  #pragma unroll
  for (int G = 0; G < 4; ++G)
    #pragma unroll
    for (int i = 0; i < 4; ++i)
      hr[G][i] = hidden[(size_t)((G << 4) + drow + i) * NU + myu];

  u64 s0[32], s1[32];
  float xz0[4], xr0[4], xh0[4], xz1[4], xr1[4], xh1[4];
  LOADSLABS(s0, 0, 0);
  LOADXP(xz0, xr0, xh0, 0, 0);

  for (int t = 0; t < NS; ++t) {
    const int tn = (t + 1 < NS) ? t + 1 : 0;   // wrap target is read-valid, unused
    PHASE(t, 0, s0, s1, xz0, xr0, xh0, xz1, xr1, xh1, 1, t);
    PHASE(t, 1, s1, s0, xz1, xr1, xh1, xz0, xr0, xh0, 2, t);
    PHASE(t, 2, s0, s1, xz0, xr0, xh0, xz1, xr1, xh1, 3, t);
    PHASE(t, 3, s1, s0, xz1, xr1, xh1, xz0, xr0, xh0, 0, tn);
  }
}

extern "C" void kernel_launch(void* const* d_in, const int* in_sizes, int n_in,
                              void* d_out, int out_size, void* d_ws, size_t ws_size,
                              hipStream_t stream) {
  const int*   x      = (const int*)d_in[0];
  const float* hidden = (const float*)d_in[1];
  const float* emb    = (const float*)d_in[2];
  const float* W      = (const float*)d_in[3];
  const float* R      = (const float*)d_in[4];
  const float* bias   = (const float*)d_in[5];
  float* out = (float*)d_out;

  char* ws = (char*)d_ws;
  float* xp  = (float*)ws;                            // 50,331,648 B
  u16*   hx  = (u16*)(ws + 50331648);                 //  8,388,608 B (128 slots)

  init_kernel<<<NB, NU, 0, stream>>>(hidden, hx);
  dim3 gA(N3 / 64, (NB * NS) / 64);
  xproj_kernel<<<gA, 256, 0, stream>>>(x, emb, W, bias, xp);
  gru_scan_kernel<<<16, 128, 0, stream>>>(xp, hidden, R, bias, out, hx);
}

// Round 10
// 1437.087 us; speedup vs baseline: 2.0515x; 1.4105x over previous
//
#include <hip/hip_runtime.h>
#include <hip/hip_bf16.h>

#define NB   64     // batch
#define NS   128    // seq len
#define ND   256    // embed dim
#define NU   512    // hidden units
#define N3   1536   // 3*NU
#define KFAST 8     // bounded sc0 poll rounds before agent-scope fallback

typedef __attribute__((ext_vector_type(4))) float  f32x4;
typedef __attribute__((ext_vector_type(8))) short  s16x8;
typedef __attribute__((ext_vector_type(4))) unsigned int u32x4;
typedef unsigned long long u64;
typedef unsigned int       u32;
typedef unsigned short     u16;

// bf16 NaN sentinel: legit h in [-1,1] -> bit14 clear; sentinel has bit14 set.
#define SENT64   0x7FC07FC07FC07FC0ull
#define BIT14x2  0x40004000u

__device__ __forceinline__ u16 f2bf(float v) {
  unsigned u = __builtin_bit_cast(unsigned, v);
  u += 0x7fffu + ((u >> 16) & 1u);          // round-to-nearest-even
  return (u16)(u >> 16);
}

// sc0 load: bypass L1, read own-XCD L2
#define LD16_SC0(dst, a, off)                                                   \
  asm volatile("global_load_dwordx4 %0, %1, off offset:" #off " sc0"            \
               : "=v"(dst) : "v"(a))

#define ISSUE_SLABS(SL_, A_) do {                                               \
    LD16_SC0(SL_[0],  A_, 0);    LD16_SC0(SL_[1],  A_, 64);                     \
    LD16_SC0(SL_[2],  A_, 128);  LD16_SC0(SL_[3],  A_, 192);                    \
    LD16_SC0(SL_[4],  A_, 256);  LD16_SC0(SL_[5],  A_, 320);                    \
    LD16_SC0(SL_[6],  A_, 384);  LD16_SC0(SL_[7],  A_, 448);                    \
    LD16_SC0(SL_[8],  A_, 512);  LD16_SC0(SL_[9],  A_, 576);                    \
    LD16_SC0(SL_[10], A_, 640);  LD16_SC0(SL_[11], A_, 704);                    \
    LD16_SC0(SL_[12], A_, 768);  LD16_SC0(SL_[13], A_, 832);                    \
    LD16_SC0(SL_[14], A_, 896);  LD16_SC0(SL_[15], A_, 960);                    \
    asm volatile("s_waitcnt vmcnt(0)" ::: "memory");                            \
    __builtin_amdgcn_sched_barrier(0);                                          \
  } while (0)

#define ORMASK(M_, SL_) do {                                                    \
    M_ = 0;                                                                     \
    _Pragma("unroll")                                                           \
    for (int q_ = 0; q_ < 16; ++q_)                                             \
      M_ |= SL_[q_][0] | SL_[q_][1] | SL_[q_][2] | SL_[q_][3];                  \
  } while (0)

// -------- init: hx slot0 = bf16(hidden); slots 1..127 = sentinel ---------------
__global__ __launch_bounds__(512) void init_kernel(const float* __restrict__ hidden,
                                                   u16* __restrict__ hx) {
  const int tid = blockIdx.x * 512 + threadIdx.x;    // 64*512 = 32768 = NB*NU
  hx[tid] = f2bf(hidden[tid]);                       // slot 0 (t=0)
  u64* fill = (u64*)(hx + NB * NU);
  const int n = 127 * NB * NU / 4;
  for (int i = tid; i < n; i += NB * NU) fill[i] = SENT64;
}

// -------- phase 1: xp = gather(emb,x) @ W + b_in  (f32 SIMT, unchanged) --------
__global__ __launch_bounds__(256) void xproj_kernel(
    const int* __restrict__ x, const float* __restrict__ emb,
    const float* __restrict__ W, const float* __restrict__ bias,
    float* __restrict__ xp) {
  __shared__ float As[32][68];
  __shared__ float Bs[32][68];
  __shared__ int tok[64];
  const int tid = threadIdx.x;
  const int m0 = blockIdx.y * 64;
  const int n0 = blockIdx.x * 64;
  if (tid < 64) tok[tid] = x[m0 + tid];
  __syncthreads();
  const int tx = tid & 15, ty = tid >> 4;
  float acc[4][4] = {};
  for (int k0 = 0; k0 < ND; k0 += 32) {
    {
      const int m = tid & 63, kq = tid >> 6;
      const float* src = emb + (size_t)tok[m] * ND + k0 + kq * 8;
      const float4 v0 = *(const float4*)(src);
      const float4 v1 = *(const float4*)(src + 4);
      As[kq*8+0][m] = v0.x; As[kq*8+1][m] = v0.y;
      As[kq*8+2][m] = v0.z; As[kq*8+3][m] = v0.w;
      As[kq*8+4][m] = v1.x; As[kq*8+5][m] = v1.y;
      As[kq*8+6][m] = v1.z; As[kq*8+7][m] = v1.w;
    }
    {
      const int n = (tid & 15) * 4, k = tid >> 4;
      *(float4*)&Bs[k][n]    = *(const float4*)&W[(size_t)(k0 + k) * N3 + n0 + n];
      *(float4*)&Bs[k+16][n] = *(const float4*)&W[(size_t)(k0 + k + 16) * N3 + n0 + n];
    }
    __syncthreads();
    #pragma unroll
    for (int kk = 0; kk < 32; ++kk) {
      const float4 b4 = *(const float4*)&Bs[kk][tx * 4];
      float a[4];
      #pragma unroll
      for (int i = 0; i < 4; ++i) a[i] = As[kk][ty * 4 + i];
      #pragma unroll
      for (int i = 0; i < 4; ++i) {
        acc[i][0] += a[i] * b4.x;
        acc[i][1] += a[i] * b4.y;
        acc[i][2] += a[i] * b4.z;
        acc[i][3] += a[i] * b4.w;
      }
    }
    __syncthreads();
  }
  #pragma unroll
  for (int i = 0; i < 4; ++i) {
    const size_t row = (size_t)(m0 + ty * 4 + i) * N3 + n0 + tx * 4;
    float4 o;
    o.x = acc[i][0] + bias[n0 + tx*4 + 0];
    o.y = acc[i][1] + bias[n0 + tx*4 + 1];
    o.z = acc[i][2] + bias[n0 + tx*4 + 2];
    o.w = acc[i][3] + bias[n0 + tx*4 + 3];
    *(float4*)&xp[row] = o;
  }
}

// -------- phase 2: persistent GRU scan, XCD-local fast path + safe fallback ----
// 128 blocks: chain g = bid&7 (8 chains x 8 batches), role = bid>>3 (16 unit-
// blocks x 32 units). Round-robin dispatch puts all 16 blocks of chain g on XCD
// g (heuristic, not required for correctness). h-exchange: producers store h
// with sc0 (write-through to local L2, fast path) AND agent-scope atomic (LLC,
// guaranteed path) to the SAME address. Consumers poll sc0 up to KFAST rounds,
// then fall back to agent-scope loads. Sentinel poll-on-data; hang-proof.
__global__ __launch_bounds__(128, 1) void gru_scan_kernel(
    const float* __restrict__ xp, const float* __restrict__ hidden,
    const float* __restrict__ R, const float* __restrict__ bias,
    float* __restrict__ out, u16* __restrict__ hx) {
  __shared__ u16 Rt[96][520];   // [c][k]: c = wv*48 + gate*16 + cu

  const int bid = blockIdx.x;
  const int g   = bid & 7;           // chain id (== XCD under round-robin)
  const int u0  = (bid >> 3) * 32;   // unit base of this block
  const int tid = threadIdx.x;
  const int lane = tid & 63;
  const int wv   = tid >> 6;

  // one-time: stage R columns transposed to bf16, remapped per-wave
  for (int idx = tid; idx < 512 * 128; idx += 128) {
    const int k = idx >> 7, c = idx & 127;
    if (c < 96) {
      const int wc = c / 48, r = c % 48, j = r >> 4, cuu = r & 15;
      Rt[c][k] = f2bf(R[(size_t)k * N3 + (j << 9) + u0 + (wc << 4) + cuu]);
    }
  }
  __syncthreads();

  const int ar8 = lane & 7;               // A row (batch in chain; rows 8-15 dup)
  const int kg  = lane >> 4;              // k-group
  const int cu  = lane & 15;              // unit within wave slice
  const int myu = u0 + (wv << 4) + cu;    // my global unit
  const int drow = kg << 2;               // D-row base; real batches iff kg<2
  const int cb  = wv * 48 + cu;           // Rt row base
  const int gateln = (kg < 2);            // lane owns 4 (batch,unit) cells

  const float bz = bias[N3 + myu];
  const float br = bias[N3 + 512 + myu];
  const float bh = bias[N3 + 1024 + myu];

  float hr[4] = {0.f, 0.f, 0.f, 0.f};
  if (gateln) {
    #pragma unroll
    for (int i = 0; i < 4; ++i)
      hr[i] = hidden[(size_t)(g * 8 + drow + i) * NU + myu];
  }

  for (int t = 0; t < NS; ++t) {
    // xp prefetch (gate lanes only; issued before the poll to overlap)
    float xz[4], xr[4], xh[4];
    if (gateln) {
      #pragma unroll
      for (int i = 0; i < 4; ++i) {
        const float* q = xp + ((size_t)((g * 8 + drow + i) * NS) + t) * N3 + myu;
        xz[i] = q[0]; xr[i] = q[512]; xh[i] = q[1024];
      }
    }

    // ---- poll-on-data: bounded sc0 fast path, then agent-scope fallback ----
    u32x4 sl[16];
    const u64 abase = (u64)((const char*)(hx + ((size_t)t * NB + g * 8 + ar8) * NU)
                            + kg * 16);
    int done = 0;
    for (int rnd = 0; rnd < KFAST; ++rnd) {
      ISSUE_SLABS(sl, abase);
      u32 m; ORMASK(m, sl);
      done = __all(((m & BIT14x2) == 0) ? 1 : 0) ? 1 : 0;
      if (done) break;
    }
    if (!done) {
      const u64* hq = (const u64*)abase;
      while (!done) {
        __builtin_amdgcn_s_sleep(1);
        #pragma unroll
        for (int ks = 0; ks < 16; ++ks) {
          union { u64 q[2]; u32x4 v; } w;
          w.q[0] = __hip_atomic_load(&hq[ks * 8],     __ATOMIC_RELAXED, __HIP_MEMORY_SCOPE_AGENT);
          w.q[1] = __hip_atomic_load(&hq[ks * 8 + 1], __ATOMIC_RELAXED, __HIP_MEMORY_SCOPE_AGENT);
          sl[ks] = w.v;
        }
        u32 m; ORMASK(m, sl);
        done = __all(((m & BIT14x2) == 0) ? 1 : 0) ? 1 : 0;
      }
    }

    // ---- 48 MFMAs: my 16 units x 3 gates ----
    f32x4 a0 = {0.f,0.f,0.f,0.f}, a1 = a0, a2 = a0;
    #pragma unroll
    for (int ks = 0; ks < 16; ++ks) {
      const s16x8 af = __builtin_bit_cast(s16x8, sl[ks]);
      const int kb = (ks << 5) + (kg << 3);
      a0 = __builtin_amdgcn_mfma_f32_16x16x32_bf16(af, *(const s16x8*)&Rt[cb][kb],      a0, 0,0,0);
      a1 = __builtin_amdgcn_mfma_f32_16x16x32_bf16(af, *(const s16x8*)&Rt[cb + 16][kb], a1, 0,0,0);
      a2 = __builtin_amdgcn_mfma_f32_16x16x32_bf16(af, *(const s16x8*)&Rt[cb + 32][kb], a2, 0,0,0);
    }

    if (gateln) {
      #pragma unroll
      for (int i = 0; i < 4; ++i) {
        const float z = 1.f / (1.f + __expf(-(xz[i] + a0[i] + bz)));
        const float r = 1.f / (1.f + __expf(-(xr[i] + a1[i] + br)));
        const float e = __expf(2.f * (xh[i] + r * (a2[i] + bh)));
        const float hh = 1.f - 2.f / (e + 1.f);     // tanh, never NaN/Inf
        hr[i] = z * hr[i] + (1.f - z) * hh;
      }
      if (t < NS - 1) {
        // dual-store h: sc0 (local L2 fast path) + agent atomic (LLC guarantee)
        #pragma unroll
        for (int i = 0; i < 4; ++i) {
          u16* dst = &hx[((size_t)(t + 1) * NB + g * 8 + drow + i) * NU + myu];
          const u32 dv = (u32)f2bf(hr[i]);
          const u64 ad = (u64)dst;
          asm volatile("global_store_short %0, %1, off sc0"
                       :: "v"(ad), "v"(dv) : "memory");
          __hip_atomic_store(dst, (u16)dv, __ATOMIC_RELAXED, __HIP_MEMORY_SCOPE_AGENT);
        }
      }
      #pragma unroll
      for (int i = 0; i < 4; ++i)
        out[((size_t)(g * 8 + drow + i) * NS + t) * NU + myu] = hr[i];
      if (t == NS - 1) {
        #pragma unroll
        for (int i = 0; i < 4; ++i)
          out[(size_t)NB * NS * NU + (size_t)(g * 8 + drow + i) * NU + myu] = hr[i];
      }
    }
  }
}

extern "C" void kernel_launch(void* const* d_in, const int* in_sizes, int n_in,
                              void* d_out, int out_size, void* d_ws, size_t ws_size,
                              hipStream_t stream) {
  const int*   x      = (const int*)d_in[0];
  const float* hidden = (const float*)d_in[1];
  const float* emb    = (const float*)d_in[2];
  const float* W      = (const float*)d_in[3];
  const float* R      = (const float*)d_in[4];
  const float* bias   = (const float*)d_in[5];
  float* out = (float*)d_out;

  char* ws = (char*)d_ws;
  float* xp = (float*)ws;                           // 50,331,648 B
  u16*   hx = (u16*)(ws + 50331648);                //  8,388,608 B (128 slots)

  init_kernel<<<NB, NU, 0, stream>>>(hidden, hx);
  dim3 gA(N3 / 64, (NB * NS) / 64);
  xproj_kernel<<<gA, 256, 0, stream>>>(x, emb, W, bias, xp);
  gru_scan_kernel<<<128, 128, 0, stream>>>(xp, hidden, R, bias, out, hx);
}

// Round 12
// 849.619 us; speedup vs baseline: 3.4700x; 1.6914x over previous
//
#include <hip/hip_runtime.h>
#include <hip/hip_bf16.h>

#define NB   64     // batch
#define NS   128    // seq len
#define ND   256    // embed dim
#define NU   512    // hidden units
#define N3   1536   // 3*NU
#define KPROBE 4    // bounded speculative sentinel rounds before flag fallback

typedef __attribute__((ext_vector_type(4))) float  f32x4;
typedef __attribute__((ext_vector_type(8))) short  s16x8;
typedef unsigned long long u64;
typedef unsigned int       u32;
typedef unsigned short     u16;

// bf16 NaN sentinel: legit h in [-1,1] -> bit14 clear; sentinel has bit14 set.
#define SENT64  0x7FC07FC07FC07FC0ull
#define BIT14x4 0x4000400040004000ull

__device__ __forceinline__ u16 f2bf(float v) {
  unsigned u = __builtin_bit_cast(unsigned, v);
  u += 0x7fffu + ((u >> 16) & 1u);          // round-to-nearest-even
  return (u16)(u >> 16);
}

// -------- init: hx slot0 = bf16(hidden); slots 1..127 = sentinel; cnt = 0 ------
__global__ __launch_bounds__(512) void init_kernel(const float* __restrict__ hidden,
                                                   u16* __restrict__ hx,
                                                   u32* __restrict__ cnt) {
  const int tid = blockIdx.x * 512 + threadIdx.x;    // 64*512 = 32768 = NB*NU
  hx[tid] = f2bf(hidden[tid]);                       // slot 0 (t=0)
  u64* fill = (u64*)(hx + NB * NU);
  const int n = 127 * NB * NU / 4;
  for (int i = tid; i < n; i += NB * NU) fill[i] = SENT64;
  if (tid < 4 * NS) cnt[tid] = 0u;                   // 4 groups * 128 steps
}

// -------- phase 1: xp = gather(emb,x) @ W + b_in  (f32 SIMT, unchanged) --------
__global__ __launch_bounds__(256) void xproj_kernel(
    const int* __restrict__ x, const float* __restrict__ emb,
    const float* __restrict__ W, const float* __restrict__ bias,
    float* __restrict__ xp) {
  __shared__ float As[32][68];
  __shared__ float Bs[32][68];
  __shared__ int tok[64];
  const int tid = threadIdx.x;
  const int m0 = blockIdx.y * 64;
  const int n0 = blockIdx.x * 64;
  if (tid < 64) tok[tid] = x[m0 + tid];
  __syncthreads();
  const int tx = tid & 15, ty = tid >> 4;
  float acc[4][4] = {};
  for (int k0 = 0; k0 < ND; k0 += 32) {
    {
      const int m = tid & 63, kq = tid >> 6;
      const float* src = emb + (size_t)tok[m] * ND + k0 + kq * 8;
      const float4 v0 = *(const float4*)(src);
      const float4 v1 = *(const float4*)(src + 4);
      As[kq*8+0][m] = v0.x; As[kq*8+1][m] = v0.y;
      As[kq*8+2][m] = v0.z; As[kq*8+3][m] = v0.w;
      As[kq*8+4][m] = v1.x; As[kq*8+5][m] = v1.y;
      As[kq*8+6][m] = v1.z; As[kq*8+7][m] = v1.w;
    }
    {
      const int n = (tid & 15) * 4, k = tid >> 4;
      *(float4*)&Bs[k][n]    = *(const float4*)&W[(size_t)(k0 + k) * N3 + n0 + n];
      *(float4*)&Bs[k+16][n] = *(const float4*)&W[(size_t)(k0 + k + 16) * N3 + n0 + n];
    }
    __syncthreads();
    #pragma unroll
    for (int kk = 0; kk < 32; ++kk) {
      const float4 b4 = *(const float4*)&Bs[kk][tx * 4];
      float a[4];
      #pragma unroll
      for (int i = 0; i < 4; ++i) a[i] = As[kk][ty * 4 + i];
      #pragma unroll
      for (int i = 0; i < 4; ++i) {
        acc[i][0] += a[i] * b4.x;
        acc[i][1] += a[i] * b4.y;
        acc[i][2] += a[i] * b4.z;
        acc[i][3] += a[i] * b4.w;
      }
    }
    __syncthreads();
  }
  #pragma unroll
  for (int i = 0; i < 4; ++i) {
    const size_t row = (size_t)(m0 + ty * 4 + i) * N3 + n0 + tx * 4;
    float4 o;
    o.x = acc[i][0] + bias[n0 + tx*4 + 0];
    o.y = acc[i][1] + bias[n0 + tx*4 + 1];
    o.z = acc[i][2] + bias[n0 + tx*4 + 2];
    o.w = acc[i][3] + bias[n0 + tx*4 + 3];
    *(float4*)&xp[row] = o;
  }
}

// -------- phase 2: persistent GRU scan: speculative sentinel + flag fallback ---
// 64 blocks = 4 groups (16 batches) x 16 unit-blocks (32 units); each wave owns
// 16 units end-to-end (gates read MFMA accumulators directly). Consumer first
// probes the h-data itself (<=KPROBE bounded sentinel rounds, C-level atomic
// loads); a clean round skips the whole drain+flag+reload chain (~1.5-2 LLC
// RTs). Otherwise it falls back to the PROVEN R5 path: wave-uniform counter
// poll, then guaranteed re-load. Producers: fire h-stores, drain, counter-add.
__global__ __launch_bounds__(128) void gru_scan_kernel(
    const float* __restrict__ xp, const float* __restrict__ hidden,
    const float* __restrict__ R, const float* __restrict__ bias,
    float* __restrict__ out, u16* __restrict__ hx,
    u32* __restrict__ cnt) {
  __shared__ u16 Rt[96][520];   // [c][k]: c = wv*48 + gate*16 + cu

  const int bid = blockIdx.x;
  const int g   = bid >> 4;          // batch group 0..3
  const int u0  = (bid & 15) * 32;   // unit base of this block
  const int tid = threadIdx.x;
  const int lane = tid & 63;
  const int wv   = tid >> 6;

  // one-time: stage R columns transposed to bf16, remapped per-wave
  for (int idx = tid; idx < 512 * 128; idx += 128) {
    const int k = idx >> 7, c = idx & 127;
    if (c < 96) {
      const int wc = c / 48, r = c % 48, j = r >> 4, cuu = r & 15;
      Rt[c][k] = f2bf(R[(size_t)k * N3 + (j << 9) + u0 + (wc << 4) + cuu]);
    }
  }
  __syncthreads();

  const int ar  = lane & 15;          // A row (batch within group)
  const int kg  = lane >> 4;          // k-group
  const int cu  = lane & 15;          // unit within wave slice
  const int myu = u0 + (wv << 4) + cu;   // my global unit
  const int drow = kg << 2;           // batch base for D rows
  const int cb  = wv * 48 + cu;       // Rt row base (gate tile j at cb + 16j)

  const float bz = bias[N3 + myu];
  const float br = bias[N3 + 512 + myu];
  const float bh = bias[N3 + 1024 + myu];

  float hr[4];
  #pragma unroll
  for (int i = 0; i < 4; ++i)
    hr[i] = hidden[(size_t)((g << 4) + drow + i) * NU + myu];

  for (int t = 0; t < NS; ++t) {
    // xp prefetch: 4 batches x 3 gates, my unit (issued before any waiting)
    float xg0[4], xg1[4], xg2[4];
    #pragma unroll
    for (int i = 0; i < 4; ++i) {
      const float* q = xp + ((size_t)(((g << 4) + drow + i) * NS) + t) * N3 + myu;
      xg0[i] = q[0]; xg1[i] = q[512]; xg2[i] = q[1024];
    }

    // ---- speculative sentinel data-probe (bounded), then flag fallback ----
    u64 alo[16], ahi[16];
    const u64* hrow = (const u64*)(hx + ((size_t)t * NB + (g << 4) + ar) * NU);
    int done = 0;
    for (int rnd = 0; rnd < KPROBE && !done; ++rnd) {
      #pragma unroll
      for (int ks = 0; ks < 16; ++ks) {
        const int qi = (ks << 3) + (kg << 1);
        alo[ks] = __hip_atomic_load(&hrow[qi],     __ATOMIC_RELAXED, __HIP_MEMORY_SCOPE_AGENT);
        ahi[ks] = __hip_atomic_load(&hrow[qi + 1], __ATOMIC_RELAXED, __HIP_MEMORY_SCOPE_AGENT);
      }
      u64 m = 0;
      #pragma unroll
      for (int ks = 0; ks < 16; ++ks) m |= alo[ks] | ahi[ks];
      done = __all(((m & BIT14x4) == 0) ? 1 : 0) ? 1 : 0;
    }
    if (!done && t > 0) {
      // authoritative fallback (proven R5 path): wave-uniform counter poll
      const u32* c = &cnt[g * NS + (t - 1)];
      while (__hip_atomic_load(c, __ATOMIC_RELAXED,
                               __HIP_MEMORY_SCOPE_AGENT) != 32u) {}
      asm volatile("" ::: "memory");
      #pragma unroll
      for (int ks = 0; ks < 16; ++ks) {   // guaranteed-valid reload
        const int qi = (ks << 3) + (kg << 1);
        alo[ks] = __hip_atomic_load(&hrow[qi],     __ATOMIC_RELAXED, __HIP_MEMORY_SCOPE_AGENT);
        ahi[ks] = __hip_atomic_load(&hrow[qi + 1], __ATOMIC_RELAXED, __HIP_MEMORY_SCOPE_AGENT);
      }
    }

    // rp for my 16 units x 3 gates: 48 MFMAs, accumulators only
    f32x4 a0 = {0.f,0.f,0.f,0.f}, a1 = a0, a2 = a0;
    #pragma unroll
    for (int ks = 0; ks < 16; ++ks) {
      union { u64 q[2]; s16x8 v; } af;
      af.q[0] = alo[ks]; af.q[1] = ahi[ks];
      const int kb = (ks << 5) + (kg << 3);
      a0 = __builtin_amdgcn_mfma_f32_16x16x32_bf16(af.v, *(const s16x8*)&Rt[cb][kb],      a0, 0,0,0);
      a1 = __builtin_amdgcn_mfma_f32_16x16x32_bf16(af.v, *(const s16x8*)&Rt[cb + 16][kb], a1, 0,0,0);
      a2 = __builtin_amdgcn_mfma_f32_16x16x32_bf16(af.v, *(const s16x8*)&Rt[cb + 32][kb], a2, 0,0,0);
    }

    // gates straight from accumulators; overflow-proof tanh keeps h in [-1,1]
    // (=> bit-14-clear bf16, so the sentinel test stays exact)
    #pragma unroll
    for (int i = 0; i < 4; ++i) {
      const float z = 1.f / (1.f + __expf(-(xg0[i] + a0[i] + bz)));
      const float r = 1.f / (1.f + __expf(-(xg1[i] + a1[i] + br)));
      const float e = __expf(2.f * (xg2[i] + r * (a2[i] + bh)));
      const float hh = 1.f - 2.f / (e + 1.f);     // tanh, never NaN/Inf
      hr[i] = z * hr[i] + (1.f - z) * hh;
    }

    if (t < NS - 1) {   // h-stores -> drain -> counter add (fallback authority)
      #pragma unroll
      for (int i = 0; i < 4; ++i)
        __hip_atomic_store(&hx[((size_t)(t + 1) * NB + (g << 4) + drow + i) * NU + myu],
                           f2bf(hr[i]), __ATOMIC_RELAXED, __HIP_MEMORY_SCOPE_AGENT);
      asm volatile("s_waitcnt vmcnt(0)" ::: "memory");
      if (lane == 0)
        __hip_atomic_fetch_add(&cnt[g * NS + t], 1u,
                               __ATOMIC_RELAXED, __HIP_MEMORY_SCOPE_AGENT);
    }

    // out stores AFTER the signal (drained by next step's vmcnt(0))
    #pragma unroll
    for (int i = 0; i < 4; ++i)
      out[((size_t)((g << 4) + drow + i) * NS + t) * NU + myu] = hr[i];
    if (t == NS - 1) {
      #pragma unroll
      for (int i = 0; i < 4; ++i)
        out[(size_t)NB * NS * NU + (size_t)((g << 4) + drow + i) * NU + myu] = hr[i];
    }
  }
}

extern "C" void kernel_launch(void* const* d_in, const int* in_sizes, int n_in,
                              void* d_out, int out_size, void* d_ws, size_t ws_size,
                              hipStream_t stream) {
  const int*   x      = (const int*)d_in[0];
  const float* hidden = (const float*)d_in[1];
  const float* emb    = (const float*)d_in[2];
  const float* W      = (const float*)d_in[3];
  const float* R      = (const float*)d_in[4];
  const float* bias   = (const float*)d_in[5];
  float* out = (float*)d_out;

  char* ws = (char*)d_ws;
  float* xp  = (float*)ws;                            // 50,331,648 B
  u16*   hx  = (u16*)(ws + 50331648);                 //  8,388,608 B (128 slots)
  u32*   cnt = (u32*)(ws + 50331648 + 8388608);       //      2,048 B

  init_kernel<<<NB, NU, 0, stream>>>(hidden, hx, cnt);
  dim3 gA(N3 / 64, (NB * NS) / 64);
  xproj_kernel<<<gA, 256, 0, stream>>>(x, emb, W, bias, xp);
  gru_scan_kernel<<<64, 128, 0, stream>>>(xp, hidden, R, bias, out, hx, cnt);
}